// Round 1
// baseline (69.921 us; speedup 1.0000x reference)
//
#include <hip/hip_runtime.h>
#include <math.h>

// PointPillarFeatureNet fused:
//   K1: accumulate sum_f[9] and M[45] (= sum over masked rows of f f^T upper-tri)
//   K3: recompute per-pillar bias, folded 4-MAC linear, BN affine folded into
//       pre-scaled weights, max over slots (incl. implicit masked-slot value t), ReLU.
// ws layout (floats): [0..8] sum_f, [9..53] M upper-tri (i<=j)

#define NSLOT 32
#define NCH 64

static constexpr float kVX = 0.16f, kVY = 0.16f;
static constexpr float kXOff = 0.08f;            // VX/2 + 0.0
static constexpr float kYOff = 0.08f - 39.68f;   // VY/2 - 39.68
static constexpr float kEps = 1e-3f;

__global__ __launch_bounds__(256) void k_stats(const float* __restrict__ in,
                                               const int* __restrict__ npts,
                                               const int* __restrict__ coords,
                                               float* __restrict__ ws, int P) {
    const int tid = threadIdx.x;
    const int lane = tid & 63;
    const int slot = lane & 31;
    const int half = lane >> 5;
    const int wv = tid >> 6;
    const int gwave = blockIdx.x * 4 + wv;
    const int nwave = gridDim.x * 4;

    float sacc[9];
    float macc[45];
#pragma unroll
    for (int i = 0; i < 9; ++i) sacc[i] = 0.f;
#pragma unroll
    for (int i = 0; i < 45; ++i) macc[i] = 0.f;

    for (int pp = gwave * 2; pp < P; pp += nwave * 2) {
        const int p = pp + half;  // P is even; pp < P => p < P
        const float4 u = *reinterpret_cast<const float4*>(in + ((size_t)p * NSLOT + slot) * 4);
        // per-pillar xyz sum over ALL 32 slots (reference sums before masking)
        float sx = u.x, sy = u.y, sz = u.z;
#pragma unroll
        for (int m = 1; m <= 16; m <<= 1) {
            sx += __shfl_xor(sx, m);
            sy += __shfl_xor(sy, m);
            sz += __shfl_xor(sz, m);
        }
        const int np = npts[p];
        const float npf = (float)np;
        const float mx = sx / npf, my = sy / npf, mz = sz / npf;
        const float cx = (float)coords[p * 4 + 3] * kVX + kXOff;
        const float cy = (float)coords[p * 4 + 2] * kVY + kYOff;
        if (slot < np) {
            const float f[9] = {u.x, u.y, u.z, u.w,
                                u.x - mx, u.y - my, u.z - mz,
                                u.x - cx, u.y - cy};
            int k = 0;
#pragma unroll
            for (int i = 0; i < 9; ++i) {
                sacc[i] += f[i];
#pragma unroll
                for (int j = i; j < 9; ++j) macc[k++] += f[i] * f[j];
            }
        }
    }

    // full-wave butterfly reduce (sums both pillar halves together — fine)
#pragma unroll
    for (int i = 0; i < 9; ++i)
#pragma unroll
        for (int m = 1; m < 64; m <<= 1) sacc[i] += __shfl_xor(sacc[i], m);
#pragma unroll
    for (int i = 0; i < 45; ++i)
#pragma unroll
        for (int m = 1; m < 64; m <<= 1) macc[i] += __shfl_xor(macc[i], m);

    __shared__ float red[4][54];
    if (lane == 0) {
#pragma unroll
        for (int i = 0; i < 9; ++i) red[wv][i] = sacc[i];
#pragma unroll
        for (int i = 0; i < 45; ++i) red[wv][9 + i] = macc[i];
    }
    __syncthreads();
    if (tid < 54) {
        const float v = red[0][tid] + red[1][tid] + red[2][tid] + red[3][tid];
        atomicAdd(&ws[tid], v);
    }
}

__global__ __launch_bounds__(256) void k_out(const float* __restrict__ in,
                                             const int* __restrict__ npts,
                                             const int* __restrict__ coords,
                                             const float* __restrict__ W,
                                             const float* __restrict__ gamma,
                                             const float* __restrict__ beta,
                                             const float* __restrict__ ws,
                                             float* __restrict__ out, int P) {
    __shared__ float lds[4][128];
    const int tid = threadIdx.x;
    const int lane = tid & 63;
    const int wv = tid >> 6;
    const int gwave = blockIdx.x * 4 + wv;
    const int nwave = gridDim.x * 4;
    const int d = lane;  // output channel

    // ---- prologue: derive BN scale/shift from the 54 global sums ----
    float Wc[9];
#pragma unroll
    for (int c = 0; c < 9; ++c) Wc[c] = W[c * NCH + d];

    const float invPN = 1.0f / ((float)P * (float)NSLOT);
    float mean = 0.f;
#pragma unroll
    for (int c = 0; c < 9; ++c) mean += ws[c] * Wc[c];
    mean *= invPN;

    float e2 = 0.f;
    {
        int k = 9;
#pragma unroll
        for (int i = 0; i < 9; ++i)
#pragma unroll
            for (int j = i; j < 9; ++j) {
                const float coef = (i == j) ? 1.f : 2.f;
                e2 += coef * ws[k++] * Wc[i] * Wc[j];
            }
    }
    e2 *= invPN;
    const float var = e2 - mean * mean;
    const float s = gamma[d] * rsqrtf(var + kEps);
    const float t = beta[d] - mean * s;

    // folded, pre-scaled weights: y = s*x + t, x = u.V + b
    const float V0 = s * (Wc[0] + Wc[4] + Wc[7]);
    const float V1 = s * (Wc[1] + Wc[5] + Wc[8]);
    const float V2 = s * (Wc[2] + Wc[6]);
    const float V3 = s * Wc[3];
    const float sW4 = s * Wc[4], sW5 = s * Wc[5], sW6 = s * Wc[6];
    const float sW7 = s * Wc[7], sW8 = s * Wc[8];

    for (int p = gwave; p < P; p += nwave) {
        const float2 g = *reinterpret_cast<const float2*>(in + (size_t)p * 128 + lane * 2);
        // xyz sums over all 32 slots: even lanes hold (u.x,u.y), odd hold (u.z,u.w)
        const bool ev = !(lane & 1);
        float px = ev ? g.x : 0.f;
        float py = ev ? g.y : 0.f;
        float pz = ev ? 0.f : g.x;
#pragma unroll
        for (int m = 1; m < 64; m <<= 1) {
            px += __shfl_xor(px, m);
            py += __shfl_xor(py, m);
            pz += __shfl_xor(pz, m);
        }
        int np = npts[p];
        np = np > NSLOT ? NSLOT : np;
        const float npf = (float)np;
        const float mx = px / npf, my = py / npf, mz = pz / npf;
        const float cx = (float)coords[p * 4 + 3] * kVX + kXOff;
        const float cy = (float)coords[p * 4 + 2] * kVY + kYOff;
        // per-pillar constant: s*b + t
        const float c0 = t - (mx * sW4 + my * sW5 + mz * sW6 + cx * sW7 + cy * sW8);

        lds[wv][lane * 2] = g.x;
        lds[wv][lane * 2 + 1] = g.y;
        asm volatile("s_waitcnt lgkmcnt(0)" ::: "memory");

        // masked slots (always >=1 since np<=31) contribute exactly t
        float ymax = (np < NSLOT) ? t : -INFINITY;
        for (int n = 0; n < np; ++n) {
            const float4 u = *reinterpret_cast<const float4*>(&lds[wv][n * 4]);
            float y = c0;
            y = fmaf(u.x, V0, y);
            y = fmaf(u.y, V1, y);
            y = fmaf(u.z, V2, y);
            y = fmaf(u.w, V3, y);
            ymax = fmaxf(ymax, y);
        }
        out[(size_t)p * NCH + d] = fmaxf(ymax, 0.f);
        asm volatile("s_waitcnt lgkmcnt(0)" ::: "memory");  // drain reads before next iter's writes
    }
}

extern "C" void kernel_launch(void* const* d_in, const int* in_sizes, int n_in,
                              void* d_out, int out_size, void* d_ws, size_t ws_size,
                              hipStream_t stream) {
    const float* in = (const float*)d_in[0];
    const int* npts = (const int*)d_in[1];
    const int* coords = (const int*)d_in[2];
    const float* W = (const float*)d_in[3];
    const float* gamma = (const float*)d_in[4];
    const float* beta = (const float*)d_in[5];
    float* out = (float*)d_out;
    float* ws = (float*)d_ws;
    const int P = in_sizes[1];  // num_points has P elements

    hipMemsetAsync(ws, 0, 54 * sizeof(float), stream);
    k_stats<<<256, 256, 0, stream>>>(in, npts, coords, ws, P);
    k_out<<<1024, 256, 0, stream>>>(in, npts, coords, W, gamma, beta, ws, out, P);
}

// Round 2
// 41.753 us; speedup vs baseline: 1.6746x; 1.6746x over previous
//
#include <hip/hip_runtime.h>
#include <math.h>

// PointPillarFeatureNet fused, latency-optimized.
//  k_stats: per-pillar raw moments (S=sum u, Q=sum u u^T over valid slots,
//           T=sum xyz over ALL slots) via quad-of-lanes, then per-pillar
//           rank-1 corrections -> 54 global sums (atomics). Also stores
//           per-pillar mean (T/np) for k_out when ws_size allows.
//  k_out:   BN folded into pre-scaled weights; per-channel lane; max over
//           slots incl. implicit masked-slot value t; ReLU.
// ws layout (floats): [0..53] global sums, [64 + 4p .. 64+4p+3] pillar mean.

#define NSLOT 32
#define NCH 64

static constexpr float kVX = 0.16f, kVY = 0.16f;
static constexpr float kXOff = 0.08f;            // VX/2 + 0.0
static constexpr float kYOff = 0.08f - 39.68f;   // VY/2 - 39.68
static constexpr float kEps = 1e-3f;
static constexpr float kNegInf = -3.402823466e38f;

__global__ __launch_bounds__(256) void k_stats(const float* __restrict__ in,
                                               const int* __restrict__ npts,
                                               const int* __restrict__ coords,
                                               float* __restrict__ ws,
                                               float* __restrict__ pmean, int P) {
    const int tid = threadIdx.x;
    const int lane = tid & 63;
    const int wv = tid >> 6;
    const int sub = lane & 3;
    const int pi = blockIdx.x * 64 + wv * 16 + (lane >> 2);
    const bool valid = pi < P;

    float T0 = 0.f, T1 = 0.f, T2 = 0.f;
    float S0 = 0.f, S1 = 0.f, S2 = 0.f, S3 = 0.f;
    float Q[10];
#pragma unroll
    for (int i = 0; i < 10; ++i) Q[i] = 0.f;
    int np = 1;
    float cx = 0.f, cy = 0.f, npf = 1.f;

    if (valid) {
        np = npts[pi];
        np = np < 1 ? 1 : (np > NSLOT ? NSLOT : np);
        npf = (float)np;
        const int4 cd = *reinterpret_cast<const int4*>(coords + (size_t)pi * 4);
        cx = (float)cd.w * kVX + kXOff;
        cy = (float)cd.z * kVY + kYOff;
        const float* bp = in + (size_t)pi * 128 + sub * 4;
#pragma unroll
        for (int k = 0; k < 8; ++k) {
            const float4 u = *reinterpret_cast<const float4*>(bp + k * 16);
            const int slot = sub + k * 4;
            T0 += u.x; T1 += u.y; T2 += u.z;
            const bool m = slot < np;
            const float ax = m ? u.x : 0.f, ay = m ? u.y : 0.f;
            const float az = m ? u.z : 0.f, aw = m ? u.w : 0.f;
            S0 += ax; S1 += ay; S2 += az; S3 += aw;
            Q[0] += ax * u.x; Q[1] += ax * u.y; Q[2] += ax * u.z; Q[3] += ax * u.w;
            Q[4] += ay * u.y; Q[5] += ay * u.z; Q[6] += ay * u.w;
            Q[7] += az * u.z; Q[8] += az * u.w;
            Q[9] += aw * u.w;
        }
    }

    // combine the 4 sub-lanes of each pillar quad
#define QUADR(v) { v += __shfl_xor(v, 1); v += __shfl_xor(v, 2); }
    QUADR(T0) QUADR(T1) QUADR(T2)
    QUADR(S0) QUADR(S1) QUADR(S2) QUADR(S3)
#pragma unroll
    for (int i = 0; i < 10; ++i) QUADR(Q[i])
#undef QUADR

    float acc[54];
#pragma unroll
    for (int i = 0; i < 54; ++i) acc[i] = 0.f;

    if (valid && sub == 0) {
        const float mx = T0 / npf, my = T1 / npf, mz = T2 / npf;
        if (pmean) {
            *reinterpret_cast<float4*>(pmean + (size_t)pi * 4) =
                make_float4(mx, my, mz, 0.f);
        }
        const float AS[9] = {S0, S1, S2, S3, S0, S1, S2, S0, S1};
        const float b9[9] = {0.f, 0.f, 0.f, 0.f, -mx, -my, -mz, -cx, -cy};
        const int r9[9] = {0, 1, 2, 3, 0, 1, 2, 0, 1};
        float Qm[4][4];
        Qm[0][0] = Q[0]; Qm[0][1] = Q[1]; Qm[0][2] = Q[2]; Qm[0][3] = Q[3];
        Qm[1][0] = Q[1]; Qm[1][1] = Q[4]; Qm[1][2] = Q[5]; Qm[1][3] = Q[6];
        Qm[2][0] = Q[2]; Qm[2][1] = Q[5]; Qm[2][2] = Q[7]; Qm[2][3] = Q[8];
        Qm[3][0] = Q[3]; Qm[3][1] = Q[6]; Qm[3][2] = Q[8]; Qm[3][3] = Q[9];
#pragma unroll
        for (int i = 0; i < 9; ++i) acc[i] = AS[i] + npf * b9[i];
        int k = 54;  // fill backwards-safe: use explicit counter
        k = 9;
#pragma unroll
        for (int i = 0; i < 9; ++i)
#pragma unroll
            for (int j = i; j < 9; ++j) {
                acc[k] = Qm[r9[i]][r9[j]] + AS[i] * b9[j] + b9[i] * AS[j]
                         + npf * b9[i] * b9[j];
                ++k;
            }
    }

    // sum over the 16 sub0 lanes (others hold zeros)
#pragma unroll
    for (int i = 0; i < 54; ++i) {
        acc[i] += __shfl_xor(acc[i], 4);
        acc[i] += __shfl_xor(acc[i], 8);
        acc[i] += __shfl_xor(acc[i], 16);
        acc[i] += __shfl_xor(acc[i], 32);
    }

    __shared__ float red[4][54];
    if (lane == 0) {
#pragma unroll
        for (int i = 0; i < 54; ++i) red[wv][i] = acc[i];
    }
    __syncthreads();
    if (tid < 54)
        atomicAdd(&ws[tid], red[0][tid] + red[1][tid] + red[2][tid] + red[3][tid]);
}

template <bool MEANS>
__global__ __launch_bounds__(256) void k_out(const float* __restrict__ in,
                                             const int* __restrict__ npts,
                                             const int* __restrict__ coords,
                                             const float* __restrict__ W,
                                             const float* __restrict__ gamma,
                                             const float* __restrict__ beta,
                                             const float* __restrict__ ws,
                                             const float* __restrict__ pmean,
                                             float* __restrict__ out, int P) {
    __shared__ float lds[4][128];
    const int tid = threadIdx.x;
    const int lane = tid & 63;
    const int wv = tid >> 6;
    const int gwave = blockIdx.x * 4 + wv;
    const int nwave = gridDim.x * 4;
    const int d = lane;

    // ---- BN fold from the 54 global sums ----
    float Wc[9];
#pragma unroll
    for (int c = 0; c < 9; ++c) Wc[c] = W[c * NCH + d];

    const float invPN = 1.0f / ((float)P * (float)NSLOT);
    float mean = 0.f;
#pragma unroll
    for (int c = 0; c < 9; ++c) mean += ws[c] * Wc[c];
    mean *= invPN;

    float e2 = 0.f;
    {
        int k = 9;
#pragma unroll
        for (int i = 0; i < 9; ++i)
#pragma unroll
            for (int j = i; j < 9; ++j) {
                const float coef = (i == j) ? 1.f : 2.f;
                e2 += coef * ws[k] * Wc[i] * Wc[j];
                ++k;
            }
    }
    e2 *= invPN;
    const float var = e2 - mean * mean;
    const float s = gamma[d] * rsqrtf(var + kEps);
    const float t = beta[d] - mean * s;

    const float V0 = s * (Wc[0] + Wc[4] + Wc[7]);
    const float V1 = s * (Wc[1] + Wc[5] + Wc[8]);
    const float V2 = s * (Wc[2] + Wc[6]);
    const float V3 = s * Wc[3];
    const float sW4 = s * Wc[4], sW5 = s * Wc[5], sW6 = s * Wc[6];
    const float sW7 = s * Wc[7], sW8 = s * Wc[8];

    for (int p = gwave; p < P; p += nwave) {
        const float2 g = *reinterpret_cast<const float2*>(in + (size_t)p * 128 + lane * 2);
        int np = npts[p];
        np = np < 1 ? 1 : (np > NSLOT ? NSLOT : np);
        float mx, my, mz;
        if (MEANS) {
            const float4 mv = *reinterpret_cast<const float4*>(pmean + (size_t)p * 4);
            mx = mv.x; my = mv.y; mz = mv.z;
        } else {
            const bool ev = !(lane & 1);
            float px = ev ? g.x : 0.f;
            float py = ev ? g.y : 0.f;
            float pz = ev ? 0.f : g.x;
#pragma unroll
            for (int m = 1; m < 64; m <<= 1) {
                px += __shfl_xor(px, m);
                py += __shfl_xor(py, m);
                pz += __shfl_xor(pz, m);
            }
            const float npf = (float)np;
            mx = px / npf; my = py / npf; mz = pz / npf;
        }
        const int4 cd = *reinterpret_cast<const int4*>(coords + (size_t)p * 4);
        const float cx = (float)cd.w * kVX + kXOff;
        const float cy = (float)cd.z * kVY + kYOff;
        const float c0 = t - (mx * sW4 + my * sW5 + mz * sW6 + cx * sW7 + cy * sW8);

        lds[wv][lane * 2] = g.x;
        lds[wv][lane * 2 + 1] = g.y;
        asm volatile("s_waitcnt lgkmcnt(0)" ::: "memory");

        float ymax0 = (np < NSLOT) ? t : kNegInf;  // masked slots contribute t
        float ymax1 = kNegInf;
        const float* lrow = lds[wv];
        int n = 0;
        for (; n + 2 <= np; n += 2) {
            const float4 u0 = *reinterpret_cast<const float4*>(lrow + n * 4);
            const float4 u1 = *reinterpret_cast<const float4*>(lrow + n * 4 + 4);
            ymax0 = fmaxf(ymax0,
                fmaf(u0.x, V0, fmaf(u0.y, V1, fmaf(u0.z, V2, fmaf(u0.w, V3, c0)))));
            ymax1 = fmaxf(ymax1,
                fmaf(u1.x, V0, fmaf(u1.y, V1, fmaf(u1.z, V2, fmaf(u1.w, V3, c0)))));
        }
        if (n < np) {
            const float4 u0 = *reinterpret_cast<const float4*>(lrow + n * 4);
            ymax0 = fmaxf(ymax0,
                fmaf(u0.x, V0, fmaf(u0.y, V1, fmaf(u0.z, V2, fmaf(u0.w, V3, c0)))));
        }
        out[(size_t)p * NCH + d] = fmaxf(fmaxf(ymax0, ymax1), 0.f);
        asm volatile("s_waitcnt lgkmcnt(0)" ::: "memory");  // drain before next iter's LDS writes
    }
}

extern "C" void kernel_launch(void* const* d_in, const int* in_sizes, int n_in,
                              void* d_out, int out_size, void* d_ws, size_t ws_size,
                              hipStream_t stream) {
    const float* in = (const float*)d_in[0];
    const int* npts = (const int*)d_in[1];
    const int* coords = (const int*)d_in[2];
    const float* W = (const float*)d_in[3];
    const float* gamma = (const float*)d_in[4];
    const float* beta = (const float*)d_in[5];
    float* out = (float*)d_out;
    float* ws = (float*)d_ws;
    const int P = in_sizes[1];  // num_points has P elements

    const size_t need = (64 + 4 * (size_t)P) * sizeof(float);
    const bool means = ws_size >= need;
    float* pmean = means ? (ws + 64) : nullptr;

    hipMemsetAsync(ws, 0, 54 * sizeof(float), stream);
    const int sblocks = (P + 63) / 64;  // 64 pillars per block (4 waves x 16)
    k_stats<<<sblocks, 256, 0, stream>>>(in, npts, coords, ws, pmean, P);
    if (means) {
        k_out<true><<<2048, 256, 0, stream>>>(in, npts, coords, W, gamma, beta, ws,
                                              pmean, out, P);
    } else {
        k_out<false><<<2048, 256, 0, stream>>>(in, npts, coords, W, gamma, beta, ws,
                                               pmean, out, P);
    }
}

// Round 3
// 31.939 us; speedup vs baseline: 2.1892x; 1.3073x over previous
//
#include <hip/hip_runtime.h>
#include <math.h>

// PointPillarFeatureNet fused.
//  k_stats: per-pillar raw moments via quad-of-lanes -> per-pillar rank-1
//           corrections -> 54 global sums (8 replica sets to cut atomic
//           contention). Also stores per-pillar meta (mean, npf, cx, cy).
//  k_out:   reduce replicas once per block into LDS; BN folded into
//           pre-scaled weights; software-pipelined pillar loop; max over
//           slots incl. implicit masked-slot value t; ReLU.
// ws layout (floats): [r*64 + e], r<8, e<54 : replica sums
//                     [512 + 8p .. 512+8p+7] : pillar meta (mx,my,mz,npf,cx,cy)

#define NSLOT 32
#define NCH 64
#define NREP 8
#define META_OFF 512

static constexpr float kVX = 0.16f, kVY = 0.16f;
static constexpr float kXOff = 0.08f;            // VX/2 + 0.0
static constexpr float kYOff = 0.08f - 39.68f;   // VY/2 - 39.68
static constexpr float kEps = 1e-3f;
static constexpr float kNegInf = -3.402823466e38f;

__global__ __launch_bounds__(256) void k_stats(const float* __restrict__ in,
                                               const int* __restrict__ npts,
                                               const int* __restrict__ coords,
                                               float* __restrict__ ws,
                                               float* __restrict__ meta, int P) {
    const int tid = threadIdx.x;
    const int lane = tid & 63;
    const int wv = tid >> 6;
    const int sub = lane & 3;
    const int pi = blockIdx.x * 64 + wv * 16 + (lane >> 2);
    const bool valid = pi < P;

    float T0 = 0.f, T1 = 0.f, T2 = 0.f;
    float S0 = 0.f, S1 = 0.f, S2 = 0.f, S3 = 0.f;
    float Q[10];
#pragma unroll
    for (int i = 0; i < 10; ++i) Q[i] = 0.f;
    int np = 1;
    float cx = 0.f, cy = 0.f, npf = 1.f;

    if (valid) {
        np = npts[pi];
        np = np < 1 ? 1 : (np > NSLOT ? NSLOT : np);
        npf = (float)np;
        const int4 cd = *reinterpret_cast<const int4*>(coords + (size_t)pi * 4);
        cx = (float)cd.w * kVX + kXOff;
        cy = (float)cd.z * kVY + kYOff;
        const float* bp = in + (size_t)pi * 128 + sub * 4;
#pragma unroll
        for (int k = 0; k < 8; ++k) {
            const float4 u = *reinterpret_cast<const float4*>(bp + k * 16);
            const int slot = sub + k * 4;
            T0 += u.x; T1 += u.y; T2 += u.z;
            const bool m = slot < np;
            const float ax = m ? u.x : 0.f, ay = m ? u.y : 0.f;
            const float az = m ? u.z : 0.f, aw = m ? u.w : 0.f;
            S0 += ax; S1 += ay; S2 += az; S3 += aw;
            Q[0] += ax * u.x; Q[1] += ax * u.y; Q[2] += ax * u.z; Q[3] += ax * u.w;
            Q[4] += ay * u.y; Q[5] += ay * u.z; Q[6] += ay * u.w;
            Q[7] += az * u.z; Q[8] += az * u.w;
            Q[9] += aw * u.w;
        }
    }

#define QUADR(v) { v += __shfl_xor(v, 1); v += __shfl_xor(v, 2); }
    QUADR(T0) QUADR(T1) QUADR(T2)
    QUADR(S0) QUADR(S1) QUADR(S2) QUADR(S3)
#pragma unroll
    for (int i = 0; i < 10; ++i) QUADR(Q[i])
#undef QUADR

    float acc[54];
#pragma unroll
    for (int i = 0; i < 54; ++i) acc[i] = 0.f;

    if (valid && sub == 0) {
        const float mx = T0 / npf, my = T1 / npf, mz = T2 / npf;
        if (meta) {
            *reinterpret_cast<float4*>(meta + (size_t)pi * 8) =
                make_float4(mx, my, mz, npf);
            *reinterpret_cast<float4*>(meta + (size_t)pi * 8 + 4) =
                make_float4(cx, cy, 0.f, 0.f);
        }
        const float AS[9] = {S0, S1, S2, S3, S0, S1, S2, S0, S1};
        const float b9[9] = {0.f, 0.f, 0.f, 0.f, -mx, -my, -mz, -cx, -cy};
        const int r9[9] = {0, 1, 2, 3, 0, 1, 2, 0, 1};
        float Qm[4][4];
        Qm[0][0] = Q[0]; Qm[0][1] = Q[1]; Qm[0][2] = Q[2]; Qm[0][3] = Q[3];
        Qm[1][0] = Q[1]; Qm[1][1] = Q[4]; Qm[1][2] = Q[5]; Qm[1][3] = Q[6];
        Qm[2][0] = Q[2]; Qm[2][1] = Q[5]; Qm[2][2] = Q[7]; Qm[2][3] = Q[8];
        Qm[3][0] = Q[3]; Qm[3][1] = Q[6]; Qm[3][2] = Q[8]; Qm[3][3] = Q[9];
#pragma unroll
        for (int i = 0; i < 9; ++i) acc[i] = AS[i] + npf * b9[i];
        int k = 9;
#pragma unroll
        for (int i = 0; i < 9; ++i)
#pragma unroll
            for (int j = i; j < 9; ++j) {
                acc[k] = Qm[r9[i]][r9[j]] + AS[i] * b9[j] + b9[i] * AS[j]
                         + npf * b9[i] * b9[j];
                ++k;
            }
    }

    // reduce across the 16 quad-leader lanes (others hold zeros)
#pragma unroll
    for (int i = 0; i < 54; ++i) {
        acc[i] += __shfl_xor(acc[i], 4);
        acc[i] += __shfl_xor(acc[i], 8);
        acc[i] += __shfl_xor(acc[i], 16);
        acc[i] += __shfl_xor(acc[i], 32);
    }

    __shared__ float red[4][54];
    if (lane == 0) {
#pragma unroll
        for (int i = 0; i < 54; ++i) red[wv][i] = acc[i];
    }
    __syncthreads();
    if (tid < 54) {
        const float v = red[0][tid] + red[1][tid] + red[2][tid] + red[3][tid];
        atomicAdd(&ws[(blockIdx.x & (NREP - 1)) * 64 + tid], v);
    }
}

__device__ __forceinline__ float dot4(const float4 u, float V0, float V1,
                                      float V2, float V3, float c0) {
    return fmaf(u.x, V0, fmaf(u.y, V1, fmaf(u.z, V2, fmaf(u.w, V3, c0))));
}

template <bool MEANS>
__global__ __launch_bounds__(256) void k_out(const float* __restrict__ in,
                                             const int* __restrict__ npts,
                                             const int* __restrict__ coords,
                                             const float* __restrict__ W,
                                             const float* __restrict__ gamma,
                                             const float* __restrict__ beta,
                                             const float* __restrict__ ws,
                                             const float* __restrict__ meta,
                                             float* __restrict__ out, int P) {
    __shared__ float ssum[54];
    __shared__ float lds[4][128];
    const int tid = threadIdx.x;
    const int lane = tid & 63;
    const int wv = tid >> 6;
    const int gwave = blockIdx.x * 4 + wv;
    const int nwave = gridDim.x * 4;
    const int d = lane;

    // reduce the replica sums once per block
    if (tid < 54) {
        float v = 0.f;
#pragma unroll
        for (int r = 0; r < NREP; ++r) v += ws[r * 64 + tid];
        ssum[tid] = v;
    }
    __syncthreads();

    // ---- BN fold ----
    float Wc[9];
#pragma unroll
    for (int c = 0; c < 9; ++c) Wc[c] = W[c * NCH + d];

    const float invPN = 1.0f / ((float)P * (float)NSLOT);
    float mean = 0.f;
#pragma unroll
    for (int c = 0; c < 9; ++c) mean += ssum[c] * Wc[c];
    mean *= invPN;

    float e2 = 0.f;
    {
        int k = 9;
#pragma unroll
        for (int i = 0; i < 9; ++i)
#pragma unroll
            for (int j = i; j < 9; ++j) {
                const float coef = (i == j) ? 1.f : 2.f;
                e2 += coef * ssum[k] * Wc[i] * Wc[j];
                ++k;
            }
    }
    e2 *= invPN;
    const float var = e2 - mean * mean;
    const float s = gamma[d] * rsqrtf(var + kEps);
    const float t = beta[d] - mean * s;

    const float V0 = s * (Wc[0] + Wc[4] + Wc[7]);
    const float V1 = s * (Wc[1] + Wc[5] + Wc[8]);
    const float V2 = s * (Wc[2] + Wc[6]);
    const float V3 = s * Wc[3];
    const float sW4 = s * Wc[4], sW5 = s * Wc[5], sW6 = s * Wc[6];
    const float sW7 = s * Wc[7], sW8 = s * Wc[8];

    if (MEANS) {
        // software-pipelined pillar loop
        int p = gwave;
        float2 g = make_float2(0.f, 0.f);
        float4 m1 = make_float4(0.f, 0.f, 0.f, 1.f);
        float4 m2 = make_float4(0.f, 0.f, 0.f, 0.f);
        if (p < P) {
            g = *reinterpret_cast<const float2*>(in + (size_t)p * 128 + lane * 2);
            m1 = *reinterpret_cast<const float4*>(meta + (size_t)p * 8);
            m2 = *reinterpret_cast<const float4*>(meta + (size_t)p * 8 + 4);
        }
        while (p < P) {
            *reinterpret_cast<float2*>(&lds[wv][lane * 2]) = g;  // same-wave DS in-order
            const int pn = p + nwave;
            float2 gn = make_float2(0.f, 0.f);
            float4 m1n = make_float4(0.f, 0.f, 0.f, 1.f);
            float4 m2n = make_float4(0.f, 0.f, 0.f, 0.f);
            if (pn < P) {  // prefetch next pillar while we compute this one
                gn = *reinterpret_cast<const float2*>(in + (size_t)pn * 128 + lane * 2);
                m1n = *reinterpret_cast<const float4*>(meta + (size_t)pn * 8);
                m2n = *reinterpret_cast<const float4*>(meta + (size_t)pn * 8 + 4);
            }
            const int np = (int)m1.w;
            const float c0 = t - (m1.x * sW4 + m1.y * sW5 + m1.z * sW6 +
                                  m2.x * sW7 + m2.y * sW8);
            const float* L = lds[wv];
            float y0 = (np < NSLOT) ? t : kNegInf;  // masked slots contribute t
            float y1 = kNegInf, y2 = kNegInf, y3 = kNegInf;
            int n = 0;
            for (; n + 4 <= np; n += 4) {
                const float4 u0 = *reinterpret_cast<const float4*>(L + n * 4);
                const float4 u1 = *reinterpret_cast<const float4*>(L + n * 4 + 4);
                const float4 u2 = *reinterpret_cast<const float4*>(L + n * 4 + 8);
                const float4 u3 = *reinterpret_cast<const float4*>(L + n * 4 + 12);
                y0 = fmaxf(y0, dot4(u0, V0, V1, V2, V3, c0));
                y1 = fmaxf(y1, dot4(u1, V0, V1, V2, V3, c0));
                y2 = fmaxf(y2, dot4(u2, V0, V1, V2, V3, c0));
                y3 = fmaxf(y3, dot4(u3, V0, V1, V2, V3, c0));
            }
            for (; n < np; ++n) {
                const float4 u0 = *reinterpret_cast<const float4*>(L + n * 4);
                y0 = fmaxf(y0, dot4(u0, V0, V1, V2, V3, c0));
            }
            out[(size_t)p * NCH + d] =
                fmaxf(fmaxf(fmaxf(y0, y1), fmaxf(y2, y3)), 0.f);
            p = pn; g = gn; m1 = m1n; m2 = m2n;
        }
    } else {
        for (int p = gwave; p < P; p += nwave) {
            const float2 g = *reinterpret_cast<const float2*>(in + (size_t)p * 128 + lane * 2);
            int np = npts[p];
            np = np < 1 ? 1 : (np > NSLOT ? NSLOT : np);
            const bool ev = !(lane & 1);
            float px = ev ? g.x : 0.f;
            float py = ev ? g.y : 0.f;
            float pz = ev ? 0.f : g.x;
#pragma unroll
            for (int m = 1; m < 64; m <<= 1) {
                px += __shfl_xor(px, m);
                py += __shfl_xor(py, m);
                pz += __shfl_xor(pz, m);
            }
            const float npf = (float)np;
            const float mx = px / npf, my = py / npf, mz = pz / npf;
            const int4 cd = *reinterpret_cast<const int4*>(coords + (size_t)p * 4);
            const float cx = (float)cd.w * kVX + kXOff;
            const float cy = (float)cd.z * kVY + kYOff;
            const float c0 = t - (mx * sW4 + my * sW5 + mz * sW6 + cx * sW7 + cy * sW8);
            *reinterpret_cast<float2*>(&lds[wv][lane * 2]) = g;
            const float* L = lds[wv];
            float y0 = (np < NSLOT) ? t : kNegInf;
            float y1 = kNegInf;
            int n = 0;
            for (; n + 2 <= np; n += 2) {
                const float4 u0 = *reinterpret_cast<const float4*>(L + n * 4);
                const float4 u1 = *reinterpret_cast<const float4*>(L + n * 4 + 4);
                y0 = fmaxf(y0, dot4(u0, V0, V1, V2, V3, c0));
                y1 = fmaxf(y1, dot4(u1, V0, V1, V2, V3, c0));
            }
            if (n < np) {
                const float4 u0 = *reinterpret_cast<const float4*>(L + n * 4);
                y0 = fmaxf(y0, dot4(u0, V0, V1, V2, V3, c0));
            }
            out[(size_t)p * NCH + d] = fmaxf(fmaxf(y0, y1), 0.f);
        }
    }
}

extern "C" void kernel_launch(void* const* d_in, const int* in_sizes, int n_in,
                              void* d_out, int out_size, void* d_ws, size_t ws_size,
                              hipStream_t stream) {
    const float* in = (const float*)d_in[0];
    const int* npts = (const int*)d_in[1];
    const int* coords = (const int*)d_in[2];
    const float* W = (const float*)d_in[3];
    const float* gamma = (const float*)d_in[4];
    const float* beta = (const float*)d_in[5];
    float* out = (float*)d_out;
    float* ws = (float*)d_ws;
    const int P = in_sizes[1];  // num_points has P elements

    const size_t need = (META_OFF + 8 * (size_t)P) * sizeof(float);
    const bool means = ws_size >= need;
    float* meta = means ? (ws + META_OFF) : nullptr;

    hipMemsetAsync(ws, 0, META_OFF * sizeof(float), stream);
    const int sblocks = (P + 63) / 64;  // 64 pillars per block (4 waves x 16)
    k_stats<<<sblocks, 256, 0, stream>>>(in, npts, coords, ws, meta, P);
    if (means) {
        k_out<true><<<2048, 256, 0, stream>>>(in, npts, coords, W, gamma, beta, ws,
                                              meta, out, P);
    } else {
        k_out<false><<<2048, 256, 0, stream>>>(in, npts, coords, W, gamma, beta, ws,
                                               meta, out, P);
    }
}